// Round 11
// baseline (406.813 us; speedup 1.0000x reference)
//
#include <hip/hip_runtime.h>
#include <math.h>

#define NN 50000
#define EE 800000
#define D128 128
#define LN_EPSF 1e-5f

#define NBK 12500         // buckets of 4 nodes: NN/4 exact
#define CAP 128           // edges per bucket capacity (lambda=64, 8-sigma bound)

typedef __bf16 bf16_t;
typedef __bf16 bf16x8 __attribute__((ext_vector_type(8)));
typedef float f32x4 __attribute__((ext_vector_type(4)));

// ws float layout: [0 .. NN*D128) agg ; then scalars: [s1, s2, flag(int), ...]
#define AGG_F (NN * D128)

__device__ __forceinline__ bf16x8 cvt8(float4 f0, float4 f1) {
    bf16x8 r;
    r[0] = (bf16_t)f0.x; r[1] = (bf16_t)f0.y; r[2] = (bf16_t)f0.z; r[3] = (bf16_t)f0.w;
    r[4] = (bf16_t)f1.x; r[5] = (bf16_t)f1.y; r[6] = (bf16_t)f1.z; r[7] = (bf16_t)f1.w;
    return r;
}

__device__ __forceinline__ bf16x8 zero8() {
    bf16x8 z;
    #pragma unroll
    for (int j = 0; j < 8; ++j) z[j] = (bf16_t)0.f;
    return z;
}

// Load W (fp32 [k][n]) into LDS as bf16 transposed [n][k], XOR-swizzled.
__device__ __forceinline__ void load_w_lds(const float* __restrict__ W, bf16_t* Wlds,
                                           const float* __restrict__ bias, float* b_s) {
    int tid = threadIdx.x;
    for (int i = tid; i < D128 * D128; i += 256) {
        int k = i >> 7, n = i & 127;
        Wlds[(n * D128 + k) ^ ((n & 7) << 3)] = (bf16_t)W[i];
    }
    if (tid < D128) b_s[tid] = bias[tid];
    __syncthreads();
}

// zero bucket cursors + scalar accumulators; wave 0 of block 0 detects int64
__global__ __launch_bounds__(256) void k_zero0(int* __restrict__ cursor,
                                               float* __restrict__ sc,
                                               const int* __restrict__ ei32,
                                               int* __restrict__ flag) {
    const int idx = blockIdx.x * 256 + threadIdx.x;
    if (blockIdx.x == 0 && threadIdx.x < 64) {
        unsigned long long m = __ballot(ei32[2 * threadIdx.x + 1] == 0);
        if (threadIdx.x == 0) { flag[0] = (m == ~0ULL) ? 1 : 0; sc[0] = 0.f; sc[1] = 0.f; }
    }
    for (int i = idx; i < NBK; i += gridDim.x * 256) cursor[i] = 0;
}

__device__ __forceinline__ void idx_pair(const void* ei, int is64, int e, int& sj, int& di) {
    if (is64) {
        const long long* p = (const long long*)ei;
        sj = (int)p[e]; di = (int)p[EE + e];
    } else {
        const int* p = (const int*)ei;
        sj = p[e]; di = p[EE + e];
    }
}

// single-pass bucket scatter: entry {eid, (dl<<16)|src}, dl = dst&3
__global__ __launch_bounds__(256) void k_scatter(const void* __restrict__ eidx,
                                                 const int* __restrict__ flag,
                                                 int* __restrict__ cursor,
                                                 int2* __restrict__ entries) {
    const int is64 = flag[0];
    for (int e = blockIdx.x * 256 + threadIdx.x; e < EE; e += gridDim.x * 256) {
        int sj, di;
        idx_pair(eidx, is64, e, sj, di);
        const int b = di >> 2;
        const int dl = di & 3;
        const int p = atomicAdd(&cursor[b], 1);
        if (p < CAP) entries[(size_t)b * CAP + p] = make_int2(e, (dl << 16) | sj);
    }
}

// ---- bucketed aggregation v2: one wave per 4-node bucket.
// All bucket metadata hoisted into 2 wave-wide register loads (128 entries).
// x[src] folded into the MFMA via identity B fragments (no scalar x loads).
// Complete sums in registers -> plain stores. No agg atomics, no pre-zero.
__global__ __launch_bounds__(256) void k_bagg(
    const float* __restrict__ ea, const float* __restrict__ x,
    const float* __restrict__ Wl, const float* __restrict__ bl,
    const int2* __restrict__ entries, const int* __restrict__ cursor,
    float* __restrict__ agg)
{
    __shared__ bf16_t Wlds[D128 * D128];
    __shared__ float bl_s[D128];
    load_w_lds(Wl, Wlds, bl, bl_s);

    const int lane = threadIdx.x & 63, wid = threadIdx.x >> 6;
    const int l15 = lane & 15, lg = lane >> 4;
    const int b = blockIdx.x * 4 + wid;          // 3125 blocks x 4 waves = 12500

    // identity B fragments for the x-fold (verified r6/r7/r9)
    bf16x8 id0 = zero8(), id1 = zero8();
    #pragma unroll
    for (int j = 0; j < 8; ++j) {
        if (8 * lg + j == l15)      id0[j] = (bf16_t)1.0f;
        if (8 * lg + j == l15 + 16) id1[j] = (bf16_t)1.0f;
    }
    float blv[8];
    #pragma unroll
    for (int q = 0; q < 8; ++q) blv[q] = bl_s[l15 + 16 * q];

    const int2* eb = entries + (size_t)b * CAP;
    const int cnt = min(cursor[b], CAP);
    // hoist the whole bucket's metadata; sanitize slots >= cnt (poisoned scratch)
    int2 m0 = eb[lane];
    int2 m1 = eb[64 + lane];
    if (lane >= cnt)      m0 = make_int2(0, 0);
    if (64 + lane >= cnt) m1 = make_int2(0, 0);

    const int ntiles = (cnt + 15) >> 4;

    float ns0[8], ns1[8], ns2[8], ns3[8];        // per-node column sums
    #pragma unroll
    for (int q = 0; q < 8; ++q) { ns0[q] = 0.f; ns1[q] = 0.f; ns2[q] = 0.f; ns3[q] = 0.f; }

    for (int t = 0; t < ntiles; ++t) {
        // extract this tile's 16 entries from the hoisted meta (no memory dep)
        const int sl = (t * 16 + l15) & 63;
        const bool lo = (t < 4);                 // uniform per tile
        const int ex = lo ? __shfl(m0.x, sl) : __shfl(m1.x, sl);
        const int ey = lo ? __shfl(m0.y, sl) : __shfl(m1.y, sl);
        const int eid = ex;
        const int src = ey & 0xffff;

        // per-row meta for the epilogue (ey depends only on l15 -> width-16 shfl)
        int dlr[4];
        #pragma unroll
        for (int i = 0; i < 4; ++i) dlr[i] = (__shfl(ey, lg * 4 + i, 16) >> 16) & 3;

        // issue ea + x vector loads together (one HBM round-trip per tile)
        float4 eF[8], xF[8];
        {
            const float* rp = ea + (size_t)eid * D128 + lg * 8;
            #pragma unroll
            for (int s = 0; s < 4; ++s) {
                eF[2 * s]     = *(const float4*)(rp + s * 32);
                eF[2 * s + 1] = *(const float4*)(rp + s * 32 + 4);
            }
            const float* xp = x + (size_t)src * D128 + lg * 8;
            #pragma unroll
            for (int s = 0; s < 4; ++s) {
                xF[2 * s]     = *(const float4*)(xp + s * 32);
                xF[2 * s + 1] = *(const float4*)(xp + s * 32 + 4);
            }
        }

        f32x4 acc[8];
        #pragma unroll
        for (int q = 0; q < 8; ++q) acc[q] = f32x4{0.f, 0.f, 0.f, 0.f};
        #pragma unroll
        for (int s = 0; s < 4; ++s) {
            const bf16x8 af = cvt8(eF[2 * s], eF[2 * s + 1]);
            const int kb = s * 32 + lg * 8;
            #pragma unroll
            for (int q = 0; q < 8; ++q) {
                const int col = l15 + 16 * q;
                bf16x8 bf = *(const bf16x8*)&Wlds[(col * D128 + kb) ^ ((col & 7) << 3)];
                acc[q] = __builtin_amdgcn_mfma_f32_16x16x32_bf16(af, bf, acc[q], 0, 0, 0);
            }
            const bf16x8 xf = cvt8(xF[2 * s], xF[2 * s + 1]);
            acc[2 * s]     = __builtin_amdgcn_mfma_f32_16x16x32_bf16(xf, id0, acc[2 * s], 0, 0, 0);
            acc[2 * s + 1] = __builtin_amdgcn_mfma_f32_16x16x32_bf16(xf, id1, acc[2 * s + 1], 0, 0, 0);
        }

        // epilogue: relu(acc + bl) -> select-add into the 4 node sums
        #pragma unroll
        for (int i = 0; i < 4; ++i) {
            const bool vr = (t * 16 + lg * 4 + i) < cnt;
            #pragma unroll
            for (int q = 0; q < 8; ++q) {
                float v = fmaxf(acc[q][i] + blv[q], 0.f);
                v = vr ? v : 0.f;
                ns0[q] += (dlr[i] == 0) ? v : 0.f;
                ns1[q] += (dlr[i] == 1) ? v : 0.f;
                ns2[q] += (dlr[i] == 2) ? v : 0.f;
                ns3[q] += (dlr[i] == 3) ? v : 0.f;
            }
        }
    }

    // cross-lg reduce (rows live in all 4 lane groups)
    #pragma unroll
    for (int q = 0; q < 8; ++q) {
        ns0[q] += __shfl_xor(ns0[q], 16); ns0[q] += __shfl_xor(ns0[q], 32);
        ns1[q] += __shfl_xor(ns1[q], 16); ns1[q] += __shfl_xor(ns1[q], 32);
        ns2[q] += __shfl_xor(ns2[q], 16); ns2[q] += __shfl_xor(ns2[q], 32);
        ns3[q] += __shfl_xor(ns3[q], 16); ns3[q] += __shfl_xor(ns3[q], 32);
    }
    // each lane group stores one node's full row (complete sums, plain stores)
    float* ag = agg + (size_t)(b * 4 + lg) * D128 + l15;
    if (lg == 0) {
        #pragma unroll
        for (int q = 0; q < 8; ++q) ag[16 * q] = ns0[q];
    } else if (lg == 1) {
        #pragma unroll
        for (int q = 0; q < 8; ++q) ag[16 * q] = ns1[q];
    } else if (lg == 2) {
        #pragma unroll
        for (int q = 0; q < 8; ++q) ag[16 * q] = ns2[q];
    } else {
        #pragma unroll
        for (int q = 0; q < 8; ++q) ag[16 * q] = ns3[q];
    }
}

// t = relu((x+agg) @ W1 + b1)  -> stored fp32 into d_out (scratch use)
__global__ __launch_bounds__(256) void k_mlp1(
    const float* __restrict__ x, const float* __restrict__ agg,
    const float* __restrict__ W1, const float* __restrict__ b1,
    float* __restrict__ tbuf)
{
    __shared__ bf16_t Wlds[D128 * D128];
    __shared__ float b_s[D128];
    load_w_lds(W1, Wlds, b1, b_s);

    const int lane = threadIdx.x & 63, wid = threadIdx.x >> 6;
    const int l15 = lane & 15, lg = lane >> 4;
    const int nbase = blockIdx.x * 64 + wid * 16;
    if (nbase >= NN) return;

    const int row = nbase + l15;
    bf16x8 a[4];
    if (row < NN) {
        const float* xr = x + (size_t)row * D128 + lg * 8;
        const float* gr = agg + (size_t)row * D128 + lg * 8;
        #pragma unroll
        for (int s = 0; s < 4; ++s) {
            float4 f0 = *(const float4*)(xr + s * 32);
            float4 f1 = *(const float4*)(xr + s * 32 + 4);
            float4 g0 = *(const float4*)(gr + s * 32);
            float4 g1 = *(const float4*)(gr + s * 32 + 4);
            float4 h0 = {f0.x + g0.x, f0.y + g0.y, f0.z + g0.z, f0.w + g0.w};
            float4 h1 = {f1.x + g1.x, f1.y + g1.y, f1.z + g1.z, f1.w + g1.w};
            a[s] = cvt8(h0, h1);
        }
    } else {
        #pragma unroll
        for (int s = 0; s < 4; ++s) a[s] = zero8();
    }
    f32x4 acc[8];
    #pragma unroll
    for (int t = 0; t < 8; ++t) acc[t] = f32x4{0.f, 0.f, 0.f, 0.f};
    #pragma unroll
    for (int s = 0; s < 4; ++s) {
        const int kb = s * 32 + lg * 8;
        #pragma unroll
        for (int t = 0; t < 8; ++t) {
            const int col = l15 + 16 * t;
            bf16x8 b = *(const bf16x8*)&Wlds[(col * D128 + kb) ^ ((col & 7) << 3)];
            acc[t] = __builtin_amdgcn_mfma_f32_16x16x32_bf16(a[s], b, acc[t], 0, 0, 0);
        }
    }
    #pragma unroll
    for (int i = 0; i < 4; ++i) {
        const int r = nbase + lg * 4 + i;
        if (r < NN) {
            float* tr = tbuf + (size_t)r * D128;
            #pragma unroll
            for (int t = 0; t < 8; ++t) {
                const int c = l15 + 16 * t;
                tr[c] = fmaxf(acc[t][i] + b_s[c], 0.0f);
            }
        }
    }
}

// h2 = t @ W2 + b2 + x  -> d_out (in place, row-safe) ; block partial sums -> sc
__global__ __launch_bounds__(256) void k_mlp2(
    const float* __restrict__ tbuf, const float* __restrict__ x,
    const float* __restrict__ W2, const float* __restrict__ b2,
    float* __restrict__ out, float* __restrict__ sc)
{
    __shared__ bf16_t Wlds[D128 * D128];
    __shared__ float b_s[D128];
    __shared__ float red[8];
    load_w_lds(W2, Wlds, b2, b_s);

    const int tid = threadIdx.x;
    const int lane = tid & 63, wid = tid >> 6;
    const int l15 = lane & 15, lg = lane >> 4;
    const int nbase = blockIdx.x * 64 + wid * 16;
    float s1 = 0.f, s2 = 0.f;

    if (nbase < NN) {
        const int row = nbase + l15;
        bf16x8 a[4];
        if (row < NN) {
            const float* rp = tbuf + (size_t)row * D128 + lg * 8;
            #pragma unroll
            for (int s = 0; s < 4; ++s) {
                float4 f0 = *(const float4*)(rp + s * 32);
                float4 f1 = *(const float4*)(rp + s * 32 + 4);
                a[s] = cvt8(f0, f1);
            }
        } else {
            #pragma unroll
            for (int s = 0; s < 4; ++s) a[s] = zero8();
        }
        f32x4 acc[8];
        #pragma unroll
        for (int t = 0; t < 8; ++t) acc[t] = f32x4{0.f, 0.f, 0.f, 0.f};
        #pragma unroll
        for (int s = 0; s < 4; ++s) {
            const int kb = s * 32 + lg * 8;
            #pragma unroll
            for (int t = 0; t < 8; ++t) {
                const int col = l15 + 16 * t;
                bf16x8 b = *(const bf16x8*)&Wlds[(col * D128 + kb) ^ ((col & 7) << 3)];
                acc[t] = __builtin_amdgcn_mfma_f32_16x16x32_bf16(a[s], b, acc[t], 0, 0, 0);
            }
        }
        #pragma unroll
        for (int i = 0; i < 4; ++i) {
            const int r = nbase + lg * 4 + i;
            if (r < NN) {
                #pragma unroll
                for (int t = 0; t < 8; ++t) {
                    const int c = l15 + 16 * t;
                    float v = acc[t][i] + b_s[c] + x[(size_t)r * D128 + c];
                    out[(size_t)r * D128 + c] = v;
                    s1 += v;
                    s2 += v * v;
                }
            }
        }
    }
    #pragma unroll
    for (int o = 32; o > 0; o >>= 1) {
        s1 += __shfl_xor(s1, o);
        s2 += __shfl_xor(s2, o);
    }
    if (lane == 0) { red[wid * 2] = s1; red[wid * 2 + 1] = s2; }
    __syncthreads();
    if (tid == 0) {
        float a1 = red[0] + red[2] + red[4] + red[6];
        float a2 = red[1] + red[3] + red[5] + red[7];
        unsafeAtomicAdd(&sc[0], a1);
        unsafeAtomicAdd(&sc[1], a2);
    }
}

// graph-LN + SiLU + nan_to_num, in place on d_out
__global__ __launch_bounds__(256) void k_ln(
    float* __restrict__ out, const float* __restrict__ sc,
    const float* __restrict__ lnw, const float* __restrict__ lnb)
{
    const float inv = 1.0f / (float)(NN * D128);
    const float mu = sc[0] * inv;
    const float var = sc[1] * inv - mu * mu;
    const float rstd = 1.0f / (sqrtf(fmaxf(var, 0.f)) + LN_EPSF);
    const int total = NN * D128 / 4;
    for (int idx = blockIdx.x * 256 + threadIdx.x; idx < total; idx += gridDim.x * 256) {
        float4 h = ((const float4*)out)[idx];
        const int c0 = (idx * 4) & 127;
        float4 w = *(const float4*)(lnw + c0);
        float4 bb = *(const float4*)(lnb + c0);
        float4 r;
        r.x = (h.x - mu) * rstd * w.x + bb.x;
        r.y = (h.y - mu) * rstd * w.y + bb.y;
        r.z = (h.z - mu) * rstd * w.z + bb.z;
        r.w = (h.w - mu) * rstd * w.w + bb.w;
        r.x = r.x / (1.f + __expf(-r.x));
        r.y = r.y / (1.f + __expf(-r.y));
        r.z = r.z / (1.f + __expf(-r.z));
        r.w = r.w / (1.f + __expf(-r.w));
        if (r.x != r.x) r.x = 0.f;
        if (r.y != r.y) r.y = 0.f;
        if (r.z != r.z) r.z = 0.f;
        if (r.w != r.w) r.w = 0.f;
        ((float4*)out)[idx] = r;
    }
}

extern "C" void kernel_launch(void* const* d_in, const int* in_sizes, int n_in,
                              void* d_out, int out_size, void* d_ws, size_t ws_size,
                              hipStream_t stream)
{
    const float* x   = (const float*)d_in[0];
    const void*  ei  = d_in[1];
    const float* ea  = (const float*)d_in[2];
    const float* Wl  = (const float*)d_in[3];
    const float* bl  = (const float*)d_in[4];
    const float* W1  = (const float*)d_in[5];
    const float* b1  = (const float*)d_in[6];
    const float* W2  = (const float*)d_in[7];
    const float* b2  = (const float*)d_in[8];
    const float* lnw = (const float*)d_in[9];
    const float* lnb = (const float*)d_in[10];
    float* out = (float*)d_out;

    float* agg = (float*)d_ws;
    float* sc  = agg + AGG_F;       // [0]=s1 [1]=s2, then flag
    int* flag  = (int*)(sc + 2);

    // bucket scratch lives in d_out (free until k_mlp1 overwrites it):
    // entries 12500*128*8B = 12.8 MB + cursor 50 KB << 25.6 MB
    int2* entries = (int2*)d_out;
    int* cursor   = (int*)(entries + (size_t)NBK * CAP);

    k_zero0<<<49, 256, 0, stream>>>(cursor, sc, (const int*)ei, flag);
    k_scatter<<<1024, 256, 0, stream>>>(ei, flag, cursor, entries);
    k_bagg<<<NBK / 4, 256, 0, stream>>>(ea, x, Wl, bl, entries, cursor, agg);
    // tbuf (fp32) staged in d_out (overwrites bucket scratch, now consumed)
    k_mlp1<<<(NN + 63) / 64, 256, 0, stream>>>(x, agg, W1, b1, out);
    k_mlp2<<<(NN + 63) / 64, 256, 0, stream>>>(out, x, W2, b2, out, sc);
    k_ln<<<NN * D128 / 4 / 256, 256, 0, stream>>>(out, sc, lnw, lnb);
}